// Round 1
// 376.134 us; speedup vs baseline: 1.2374x; 1.2374x over previous
//
#include <hip/hip_runtime.h>

// textPCNN fused (R6): latency-bound at 2 waves/SIMD (occ 24%, all pipes <30%).
// -> 16-wave blocks, 64x64 wave tiles (acc 64 regs, <=128 VGPR => 4 waves/SIMD),
//    frag-packed bf16 B (coalesced 1KB wave-loads, K zero-padded to 1216,
//    uniform 38-iter loop), transposed outwT + coalesced shuffle-reduce out GEMM,
//    cross-wave raw-max combine in LDS before tanh.
// R5 attribution: uncoalesced B (16 lines/instr) + uncoalesced outw (53
// lines/instr, ~98K wave-loads/block) + 2 waves/SIMD = unhidden latency.

#define XSTRIDE 424     // LDS x-row stride in bf16 elems (848 B = 53 short8)
#define XROWS 131       // 128 data + rows 128..130 zeroed (row 130: k-tail reads)
#define LPV 126
#define NC 53

typedef __attribute__((ext_vector_type(8))) short short8;
typedef __attribute__((ext_vector_type(4))) float floatx4;

__device__ __forceinline__ unsigned short f2bf_rne(float x) {
    unsigned u = __float_as_uint(x);
    u += 0x7fffu + ((u >> 16) & 1u);   // round-to-nearest-even (inputs finite)
    return (unsigned short)(u >> 16);
}

// prep: conv_w fp32 [512][3*400] -> bf16 frag-packed convwb2:
//   flat = (((ftile*38+ks)*4+kq)*16+col)*8 + e ; k=ks*32+kq*8+e, f=ftile*16+col
//   k>=1200 -> 0 (zero K tail, makes main K-loop uniform 38 iters)
// plus out_w [1536][53] -> outwT [53][1536] fp32 (coalesced epilogue reads).
__global__ void __launch_bounds__(1024)
prep(const float* __restrict__ convw, const float* __restrict__ outw,
     unsigned short* __restrict__ convwb2, float* __restrict__ outwT) {
    int i = blockIdx.x * 1024 + threadIdx.x;
    if (i < 622592) {
        int e = i & 7, col = (i >> 3) & 15, kq = (i >> 7) & 3;
        int rest = i >> 9;
        int ks = rest % 38, ftile = rest / 38;
        int k = ks * 32 + kq * 8 + e, f = ftile * 16 + col;
        convwb2[i] = (k < 1200) ? f2bf_rne(convw[f * 1200 + k])
                                : (unsigned short)0;
    } else {
        int i2 = i - 622592;
        if (i2 < 81408) {                  // 53*1536
            int c = i2 / 1536, j = i2 - c * 1536;
            outwT[i2] = outw[j * 53 + c];
        }
    }
}

extern "C" __global__ void __launch_bounds__(1024)
pcnn_fused(const int* __restrict__ tokens, const int* __restrict__ pf1,
           const int* __restrict__ pf2, const int* __restrict__ epos,
           const float* __restrict__ wordvec,
           const float* __restrict__ pf1e,
           const float* __restrict__ pf2e,
           const unsigned short* __restrict__ convwb2,  // frag-packed bf16 in ws
           const float* __restrict__ convb,
           const float* __restrict__ outwT,             // [53][1536] fp32 in ws
           const float* __restrict__ outb,
           float* __restrict__ out)
{
    extern __shared__ char smem[];
    unsigned short* xl = (unsigned short*)smem;          // 131*424 ush = 111088 B
    float* pfeat = (float*)(smem + 111088);              // [2][1536] f = 12288 B
    int*   idx   = (int*)(smem + 111088 + 12288);        // 3*128 = 1536 B

    const int n    = blockIdx.x;
    const int tid  = threadIdx.x;
    const int lane = tid & 63;
    const int wv   = tid >> 6;       // 0..15
    const int wr   = wv & 1;         // t-half: rows [64*wr, 64*wr+64)
    const int wc   = wv >> 1;        // filter group: f in [64*wc, 64*wc+64)

    // preload indices + zero rows 128..130 (window/k-tail overreads hit zeros)
    if (tid < 128) {
        int base = n * 128 + tid;
        idx[tid]       = tokens[base];
        idx[128 + tid] = pf1[base];
        idx[256 + tid] = pf2[base];
    }
    {
        const short8 z8 = {0, 0, 0, 0, 0, 0, 0, 0};
        short8* dst = (short8*)xl;                       // 53 short8 per row
        for (int i = tid; i < 159; i += 1024) {          // 3 rows * 53 chunks
            int row = 128 + i / 53, c = i % 53;
            dst[row * 53 + c] = z8;
        }
    }
    __syncthreads();

    // ---- flat gather + fp32->bf16: all iterations independent ----
    {
        const float2* wv2 = (const float2*)wordvec;      // 150 float2 per row
        const float2* p12 = (const float2*)pf1e;         // 25 float2 per row
        const float2* p22 = (const float2*)pf2e;
        #pragma unroll 4
        for (int i = tid; i < 128 * 150; i += 1024) {    // word part
            int row = i / 150, c = i - row * 150;
            float2 v = wv2[(long)idx[row] * 150 + c];
            *(ushort2*)(xl + row * XSTRIDE + 2 * c) =
                make_ushort2(f2bf_rne(v.x), f2bf_rne(v.y));
        }
        #pragma unroll 4
        for (int i = tid; i < 128 * 25; i += 1024) {     // pf1 + pf2 parts
            int row = i / 25, c = i - row * 25;
            float2 v = p12[idx[128 + row] * 25 + c];
            *(ushort2*)(xl + row * XSTRIDE + 300 + 2 * c) =
                make_ushort2(f2bf_rne(v.x), f2bf_rne(v.y));
            float2 w = p22[idx[256 + row] * 25 + c];
            *(ushort2*)(xl + row * XSTRIDE + 350 + 2 * c) =
                make_ushort2(f2bf_rne(w.x), f2bf_rne(w.y));
        }
    }
    __syncthreads();

    // ---- conv GEMM: C[128 t x 512 f]; wave owns t in [64wr,+64), f in [64wc,+64)
    // A[t][k] = xl[t + k/400][k%400] via per-lane ck wrap; B frag-packed so each
    // wave-load of b[jt] is 1KB contiguous. Uniform 38 iters (K=1216, zero tail).
    const int col = lane & 15;   // A row-in-tile / B f-in-tile / C col
    const int kq  = lane >> 4;   // k-quad: k offset 8*kq; C row = 4*kq + r

    const floatx4 fz = {0.f, 0.f, 0.f, 0.f};
    floatx4 acc[4][4];   // [mt][jt]
    #pragma unroll
    for (int mt = 0; mt < 4; ++mt)
        #pragma unroll
        for (int jt = 0; jt < 4; ++jt) acc[mt][jt] = fz;

    int ck   = kq * 8;                            // k mod 400 for this lane
    int aoff = (wr * 64 + col) * XSTRIDE + kq * 8;
    const unsigned short* bb = convwb2 + (wc * 4) * (38 * 512) + lane * 8;

    #pragma unroll 1
    for (int ks = 0; ks < 38; ++ks) {
        short8 b[4], a[4];
        #pragma unroll
        for (int jt = 0; jt < 4; ++jt)
            b[jt] = *(const short8*)(bb + jt * (38 * 512) + ks * 512);
        #pragma unroll
        for (int mt = 0; mt < 4; ++mt)
            a[mt] = *(const short8*)(xl + aoff + mt * (16 * XSTRIDE));
        __builtin_amdgcn_s_setprio(1);
        #pragma unroll
        for (int mt = 0; mt < 4; ++mt)
            #pragma unroll
            for (int jt = 0; jt < 4; ++jt)
                acc[mt][jt] = __builtin_amdgcn_mfma_f32_16x16x32_bf16(
                    a[mt], b[jt], acc[mt][jt], 0, 0, 0);
        __builtin_amdgcn_s_setprio(0);
        ck += 32; aoff += 32;
        if (ck >= 400) { ck -= 400; aoff += XSTRIDE - 400; }
    }

    // ---- pool raw acc over 3 segments within this wave's t-half ----
    const int p1 = epos[2 * n], p2 = epos[2 * n + 1];
    #pragma unroll
    for (int jt = 0; jt < 4; ++jt) {
        float m0 = -1e30f, m1 = -1e30f, m2 = -1e30f;
        #pragma unroll
        for (int mt = 0; mt < 4; ++mt) {
            #pragma unroll
            for (int r = 0; r < 4; ++r) {
                int t = wr * 64 + mt * 16 + kq * 4 + r;   // C/D row mapping
                float v = acc[mt][jt][r];
                if (t < LPV) {
                    if (t <= p1) m0 = fmaxf(m0, v);
                    if (t >= p1 && t <= p2) m1 = fmaxf(m1, v);
                    if (t >= p2) m2 = fmaxf(m2, v);
                }
            }
        }
        // lanes sharing col differ in kq (xor 16, 32): reduce t-coverage
        m0 = fmaxf(m0, __shfl_xor(m0, 16)); m0 = fmaxf(m0, __shfl_xor(m0, 32));
        m1 = fmaxf(m1, __shfl_xor(m1, 16)); m1 = fmaxf(m1, __shfl_xor(m1, 32));
        m2 = fmaxf(m2, __shfl_xor(m2, 16)); m2 = fmaxf(m2, __shfl_xor(m2, 32));
        if (kq == 0) {
            int f = wc * 64 + jt * 16 + col;
            pfeat[wr * 1536 + 3 * f + 0] = m0;   // raw max, tanh after combine
            pfeat[wr * 1536 + 3 * f + 1] = m1;
            pfeat[wr * 1536 + 3 * f + 2] = m2;
        }
    }
    __syncthreads();

    // ---- combine t-halves, add bias, tanh (monotonic: tanh(max+b)) ----
    for (int i = tid; i < 1536; i += 1024) {
        float v = fmaxf(pfeat[i], pfeat[1536 + i]);
        int f = i / 3;
        pfeat[i] = tanhf(v + convb[f]);          // in place -> feat
    }
    __syncthreads();

    // ---- out GEMM: coalesced outwT rows, lanes stride j, shuffle reduce ----
    {
        const float* feat = pfeat;
        for (int cc = wv; cc < NC; cc += 16) {
            const float* wrow = outwT + cc * 1536;
            float s = 0.f;
            #pragma unroll 4
            for (int jj = lane; jj < 1536; jj += 64)
                s += feat[jj] * wrow[jj];
            s += __shfl_xor(s, 32); s += __shfl_xor(s, 16);
            s += __shfl_xor(s, 8);  s += __shfl_xor(s, 4);
            s += __shfl_xor(s, 2);  s += __shfl_xor(s, 1);
            if (lane == 0) out[n * 53 + cc] = s + outb[cc];
        }
    }
}

extern "C" void kernel_launch(void* const* d_in, const int* in_sizes, int n_in,
                              void* d_out, int out_size, void* d_ws, size_t ws_size,
                              hipStream_t stream) {
    (void)in_sizes; (void)n_in; (void)ws_size; (void)out_size;
    const int* tokens = (const int*)d_in[0];
    const int* pf1    = (const int*)d_in[1];
    const int* pf2    = (const int*)d_in[2];
    const int* epos   = (const int*)d_in[3];
    const float* wordvec = (const float*)d_in[4];
    const float* pf1e    = (const float*)d_in[5];
    const float* pf2e    = (const float*)d_in[6];
    const float* convw   = (const float*)d_in[7];
    const float* convb   = (const float*)d_in[8];
    const float* outw    = (const float*)d_in[9];
    const float* outb    = (const float*)d_in[10];
    float* out = (float*)d_out;

    unsigned short* convwb2 = (unsigned short*)d_ws;          // 622592 ush = 1245184 B
    float* outwT = (float*)((char*)d_ws + 1245184);           // 81408 f = 325632 B

    prep<<<dim3(688), dim3(1024), 0, stream>>>(convw, outw, convwb2, outwT);

    const size_t lds_bytes = 111088 + 12288 + 1536;           // 124912
    pcnn_fused<<<dim3(1024), dim3(1024), lds_bytes, stream>>>(
        tokens, pf1, pf2, epos, wordvec, pf1e, pf2e, convwb2,
        convb, outwT, outb, out);
}

// Round 2
// 362.350 us; speedup vs baseline: 1.2845x; 1.0380x over previous
//
#include <hip/hip_runtime.h>

// textPCNN fused (R7): R6 was 1 block/CU (LDS 125KB) -> every __syncthreads
// stalls the whole CU; gather (latency, no MFMA) / GEMM / epilogue phases
// fully serialize. -> Split each sentence into 2 t-half blocks (512 thr,
// 8 waves, 64t x 64f tiles): LDS 57.6KB -> 2 blocks/CU, phases of neighbor
// blocks overlap. B-L2 traffic unchanged (t-split removes R6's wr-pair B
// duplication). Cross-half pool combine + tanh + out-GEMM moved to a small
// third kernel via raw-max ws buffer. Word gather vectorized to float4.

#define XSTRIDE 424     // LDS x-row stride in bf16 elems (848 B = 53 short8)
#define LPV 126
#define NC 53

typedef __attribute__((ext_vector_type(8))) short short8;
typedef __attribute__((ext_vector_type(4))) float floatx4;

__device__ __forceinline__ unsigned short f2bf_rne(float x) {
    unsigned u = __float_as_uint(x);
    u += 0x7fffu + ((u >> 16) & 1u);   // round-to-nearest-even (inputs finite)
    return (unsigned short)(u >> 16);
}

// prep: conv_w fp32 [512][3*400] -> bf16 frag-packed convwb2:
//   flat = (((ftile*38+ks)*4+kq)*16+col)*8 + e ; k=ks*32+kq*8+e, f=ftile*16+col
//   k>=1200 -> 0 (zero K tail, uniform 38-iter K-loop)
// plus out_w [1536][53] -> outwT [53][1536] fp32 (coalesced epilogue reads).
__global__ void __launch_bounds__(1024)
prep(const float* __restrict__ convw, const float* __restrict__ outw,
     unsigned short* __restrict__ convwb2, float* __restrict__ outwT) {
    int i = blockIdx.x * 1024 + threadIdx.x;
    if (i < 622592) {
        int e = i & 7, col = (i >> 3) & 15, kq = (i >> 7) & 3;
        int rest = i >> 9;
        int ks = rest % 38, ftile = rest / 38;
        int k = ks * 32 + kq * 8 + e, f = ftile * 16 + col;
        convwb2[i] = (k < 1200) ? f2bf_rne(convw[f * 1200 + k])
                                : (unsigned short)0;
    } else {
        int i2 = i - 622592;
        if (i2 < 81408) {                  // 53*1536
            int c = i2 / 1536, j = i2 - c * 1536;
            outwT[i2] = outw[j * 53 + c];
        }
    }
}

// kernel 2: one block per (sentence, t-half). Gather 67 x-rows -> LDS,
// conv GEMM 8 waves x (64t x 64f), pool raw 3-seg max, write to ws pfe.
extern "C" __global__ void __launch_bounds__(512, 4)
pcnn_half(const int* __restrict__ tokens, const int* __restrict__ pf1,
          const int* __restrict__ pf2, const int* __restrict__ epos,
          const float* __restrict__ wordvec,
          const float* __restrict__ pf1e,
          const float* __restrict__ pf2e,
          const unsigned short* __restrict__ convwb2,  // frag-packed bf16 in ws
          float* __restrict__ pfe)                     // [1024][2][1536] raw max
{
    extern __shared__ char smem[];
    unsigned short* xl = (unsigned short*)smem;        // 67*424 ush = 56816 B
    int* idx = (int*)(smem + 56816);                   // 3*67 ints (816 B pad)

    const int bid = blockIdx.x;
    const int n   = bid >> 1;
    const int wr  = bid & 1;        // t-half: global t in [64wr, 64wr+64)
    const int r0  = wr * 64;
    const int nreal = wr ? 64 : 67; // real x-rows this block stages

    const int tid  = threadIdx.x;
    const int lane = tid & 63;
    const int wv   = tid >> 6;      // 0..7 : f in [64wv, 64wv+64)

    if (tid < nreal) {
        int base = n * 128 + r0 + tid;
        idx[tid]       = tokens[base];
        idx[67 + tid]  = pf1[base];
        idx[134 + tid] = pf2[base];
    }
    if (wr) {   // local rows 64..66 are past end of sentence: zero them
        const short8 z8 = {0, 0, 0, 0, 0, 0, 0, 0};
        short8* dst = (short8*)xl;                     // 53 short8 per row
        for (int i = tid; i < 159; i += 512) {
            int row = 64 + i / 53, c = i % 53;
            dst[row * 53 + c] = z8;
        }
    }
    __syncthreads();

    // ---- gather + fp32->bf16 (float4 word loads; rows 16B-aligned) ----
    {
        const float4* wv4 = (const float4*)wordvec;    // 75 float4 per row
        const float2* p12 = (const float2*)pf1e;       // 25 float2 per row
        const float2* p22 = (const float2*)pf2e;
        #pragma unroll 4
        for (int i = tid; i < nreal * 75; i += 512) {  // word part
            int row = i / 75, c = i - row * 75;
            float4 v = wv4[(long)idx[row] * 75 + c];
            *(ushort4*)(xl + row * XSTRIDE + 4 * c) =
                make_ushort4(f2bf_rne(v.x), f2bf_rne(v.y),
                             f2bf_rne(v.z), f2bf_rne(v.w));
        }
        #pragma unroll 4
        for (int i = tid; i < nreal * 25; i += 512) {  // pf1 + pf2 parts
            int row = i / 25, c = i - row * 25;
            float2 v = p12[idx[67 + row] * 25 + c];
            *(ushort2*)(xl + row * XSTRIDE + 300 + 2 * c) =
                make_ushort2(f2bf_rne(v.x), f2bf_rne(v.y));
            float2 w = p22[idx[134 + row] * 25 + c];
            *(ushort2*)(xl + row * XSTRIDE + 350 + 2 * c) =
                make_ushort2(f2bf_rne(w.x), f2bf_rne(w.y));
        }
    }
    __syncthreads();

    // ---- conv GEMM: wave wv owns local t[0,64) x f[64wv, 64wv+64) ----
    // A[t][k] = xl[t + k/400][k%400]; B frag-packed (1KB coalesced wave-loads).
    const int col = lane & 15;   // A row-in-tile / B f-in-tile / C col
    const int kq  = lane >> 4;   // k-quad: k offset 8*kq; C row = 4*kq + r

    const floatx4 fz = {0.f, 0.f, 0.f, 0.f};
    floatx4 acc[4][4];   // [mt][jt]
    #pragma unroll
    for (int mt = 0; mt < 4; ++mt)
        #pragma unroll
        for (int jt = 0; jt < 4; ++jt) acc[mt][jt] = fz;

    int ck   = kq * 8;                           // k mod 400 for this lane
    int aoff = col * XSTRIDE + kq * 8;
    const unsigned short* bb = convwb2 + lane * 8;

    #pragma unroll 1
    for (int ks = 0; ks < 38; ++ks) {
        short8 b[4], a[4];
        #pragma unroll
        for (int jt = 0; jt < 4; ++jt)
            b[jt] = *(const short8*)(bb + ((wv * 4 + jt) * 38 + ks) * 512);
        #pragma unroll
        for (int mt = 0; mt < 4; ++mt)
            a[mt] = *(const short8*)(xl + aoff + mt * (16 * XSTRIDE));
        __builtin_amdgcn_s_setprio(1);
        #pragma unroll
        for (int mt = 0; mt < 4; ++mt)
            #pragma unroll
            for (int jt = 0; jt < 4; ++jt)
                acc[mt][jt] = __builtin_amdgcn_mfma_f32_16x16x32_bf16(
                    a[mt], b[jt], acc[mt][jt], 0, 0, 0);
        __builtin_amdgcn_s_setprio(0);
        ck += 32; aoff += 32;
        if (ck >= 400) { ck -= 400; aoff += XSTRIDE - 400; }
    }

    // ---- pool raw acc over 3 segments (this half's t-range), write ws ----
    const int p1 = epos[2 * n], p2 = epos[2 * n + 1];
    float* pf_out = pfe + (n * 2 + wr) * 1536;
    #pragma unroll
    for (int jt = 0; jt < 4; ++jt) {
        float m0 = -1e30f, m1 = -1e30f, m2 = -1e30f;
        #pragma unroll
        for (int mt = 0; mt < 4; ++mt) {
            #pragma unroll
            for (int r = 0; r < 4; ++r) {
                int gt = r0 + mt * 16 + kq * 4 + r;   // global t (C/D row map)
                float v = acc[mt][jt][r];
                if (gt < LPV) {
                    if (gt <= p1) m0 = fmaxf(m0, v);
                    if (gt >= p1 && gt <= p2) m1 = fmaxf(m1, v);
                    if (gt >= p2) m2 = fmaxf(m2, v);
                }
            }
        }
        // lanes sharing col differ in kq (xor 16, 32): reduce t-coverage
        m0 = fmaxf(m0, __shfl_xor(m0, 16)); m0 = fmaxf(m0, __shfl_xor(m0, 32));
        m1 = fmaxf(m1, __shfl_xor(m1, 16)); m1 = fmaxf(m1, __shfl_xor(m1, 32));
        m2 = fmaxf(m2, __shfl_xor(m2, 16)); m2 = fmaxf(m2, __shfl_xor(m2, 32));
        if (kq == 0) {
            int f = wv * 64 + jt * 16 + col;
            pf_out[3 * f + 0] = m0;    // raw max; tanh after cross-half combine
            pf_out[3 * f + 1] = m1;
            pf_out[3 * f + 2] = m2;
        }
    }
}

// kernel 3: combine t-halves, +bias, tanh, out GEMM. One block per sentence.
extern "C" __global__ void __launch_bounds__(256)
pcnn_out(const float* __restrict__ pfe, const float* __restrict__ convb,
         const float* __restrict__ outwT,            // [53][1536] fp32 in ws
         const float* __restrict__ outb, float* __restrict__ out)
{
    __shared__ float feat[1536];
    const int n = blockIdx.x;
    const int tid = threadIdx.x;
    const float* pa = pfe + n * 3072;
    const float* pb = pa + 1536;

    for (int i = tid; i < 1536; i += 256) {
        float v = fmaxf(pa[i], pb[i]);
        // tanh monotonic: max(tanh(x+b)) == tanh(max(x)+b); segs nonempty
        feat[i] = tanhf(v + convb[i / 3]);
    }
    __syncthreads();

    const int lane = tid & 63;
    const int wv   = tid >> 6;     // 0..3
    for (int cc = wv; cc < NC; cc += 4) {
        const float* wrow = outwT + cc * 1536;
        float s = 0.f;
        #pragma unroll 4
        for (int jj = lane; jj < 1536; jj += 64)
            s += feat[jj] * wrow[jj];
        s += __shfl_xor(s, 32); s += __shfl_xor(s, 16);
        s += __shfl_xor(s, 8);  s += __shfl_xor(s, 4);
        s += __shfl_xor(s, 2);  s += __shfl_xor(s, 1);
        if (lane == 0) out[n * 53 + cc] = s + outb[cc];
    }
}

extern "C" void kernel_launch(void* const* d_in, const int* in_sizes, int n_in,
                              void* d_out, int out_size, void* d_ws, size_t ws_size,
                              hipStream_t stream) {
    (void)in_sizes; (void)n_in; (void)ws_size; (void)out_size;
    const int* tokens = (const int*)d_in[0];
    const int* pf1    = (const int*)d_in[1];
    const int* pf2    = (const int*)d_in[2];
    const int* epos   = (const int*)d_in[3];
    const float* wordvec = (const float*)d_in[4];
    const float* pf1e    = (const float*)d_in[5];
    const float* pf2e    = (const float*)d_in[6];
    const float* convw   = (const float*)d_in[7];
    const float* convb   = (const float*)d_in[8];
    const float* outw    = (const float*)d_in[9];
    const float* outb    = (const float*)d_in[10];
    float* out = (float*)d_out;

    unsigned short* convwb2 = (unsigned short*)d_ws;       // 1,245,184 B
    float* outwT = (float*)((char*)d_ws + 1245184);        // 325,632 B
    float* pfe   = (float*)((char*)d_ws + 1570816);        // 1024*2*1536 f = 12.6 MB

    prep<<<dim3(688), dim3(1024), 0, stream>>>(convw, outw, convwb2, outwT);

    const size_t lds_bytes = 56816 + 816;                  // 57,632 B -> 2 blocks/CU
    pcnn_half<<<dim3(2048), dim3(512), lds_bytes, stream>>>(
        tokens, pf1, pf2, epos, wordvec, pf1e, pf2e, convwb2, pfe);

    pcnn_out<<<dim3(1024), dim3(256), 0, stream>>>(pfe, convb, outwT, outb, out);
}